// Round 11
// baseline (518.780 us; speedup 1.0000x reference)
//
#include <hip/hip_runtime.h>
#include <hip/hip_bf16.h>

// Problem: S=1024, B=512, F=128, H=3
//   xp[s,b,h] = dot(x[s,b,:], W_ih[h,:]) + b_ih[h] + b_hh[h]   (bias folded)
//   h_t = tanh(xp[t] + W_hh @ h_{t-1})
//   delta[s,b] = signal[argmax_h(h[s,b,:] + gumbel[s,b,:])]   (hard gumbel fwd)
//   out = [delta (S*B floats), h_T (B*3 floats)]

#define S_DIM 1024
#define B_DIM 512
#define F_DIM 128

// Native clang vector type: accepted by __builtin_nontemporal_load
// (HIP_vector_type float4 is NOT — round-8 compile error).
typedef float f32x4 __attribute__((ext_vector_type(4)));

// ---------------- Kernel 1: input projection + gumbel pack ------------------
// 8 lanes per row; lane c owns the contiguous 64B chunk [c*16, c*16+16) of the
// row. A wave covers 8 rows with 4 fully-coalesced dwordx4 loads (nontemporal:
// x is stream-once). 3-stage butterfly over the 8-lane group (9 ds ops per
// 8 rows). Packed output row (32B):
//   xpk[row*8 + {0,1,2}] = proj + b_ih + b_hh;  xpk[row*8 + {4,5,6}] = gumbel.
__global__ __launch_bounds__(256) void k_inproj(
    const float* __restrict__ x,       // (S,B,F)
    const float* __restrict__ gumbel,  // (S,B,3)
    const float* __restrict__ W,       // (3,128)
    const float* __restrict__ b_ih,    // (3)
    const float* __restrict__ b_hh,    // (3)
    float* __restrict__ xpk)           // (S*B, 8)
{
    int tid  = blockIdx.x * 256 + threadIdx.x;
    int row  = tid >> 3;                 // one row per 8 lanes
    int c    = tid & 7;                  // 16-float chunk within the row
    int lane = threadIdx.x & 63;
    int wbase = (tid - lane) >> 3;       // first row handled by this wave

    const f32x4* x4 = (const f32x4*)x;
    const f32x4* W4 = (const f32x4*)W;
    size_t xb = (size_t)row * 32 + (size_t)c * 4;

    f32x4 v0 = __builtin_nontemporal_load(&x4[xb + 0]);
    f32x4 v1 = __builtin_nontemporal_load(&x4[xb + 1]);
    f32x4 v2 = __builtin_nontemporal_load(&x4[xb + 2]);
    f32x4 v3 = __builtin_nontemporal_load(&x4[xb + 3]);

    float p0 = 0.f, p1 = 0.f, p2 = 0.f;
#pragma unroll
    for (int h = 0; h < 3; ++h) {
        f32x4 w0 = W4[h * 32 + c * 4 + 0];   // 1.5 KB total, L1-resident
        f32x4 w1 = W4[h * 32 + c * 4 + 1];
        f32x4 w2 = W4[h * 32 + c * 4 + 2];
        f32x4 w3 = W4[h * 32 + c * 4 + 3];
        float acc = v0.x * w0.x + v0.y * w0.y + v0.z * w0.z + v0.w * w0.w
                  + v1.x * w1.x + v1.y * w1.y + v1.z * w1.z + v1.w * w1.w
                  + v2.x * w2.x + v2.y * w2.y + v2.z * w2.z + v2.w * w2.w
                  + v3.x * w3.x + v3.y * w3.y + v3.z * w3.z + v3.w * w3.w;
        if (h == 0) p0 = acc; else if (h == 1) p1 = acc; else p2 = acc;
    }

    // Butterfly reduce within each 8-lane group (masks 1,2,4 stay in-group).
#pragma unroll
    for (int m = 1; m <= 4; m <<= 1) {
        p0 += __shfl_xor(p0, m, 64);
        p1 += __shfl_xor(p1, m, 64);
        p2 += __shfl_xor(p2, m, 64);
    }

    if (c < 3) {
        float p = (c == 0) ? p0 : ((c == 1) ? p1 : p2);
        xpk[(size_t)row * 8 + c] = p + b_ih[c] + b_hh[c];
    }

    // Gumbel: this wave's 8 rows need gumbel[wbase*3 .. wbase*3+23]
    // (24 consecutive floats -> one coalesced 96B load on lanes 0-23).
    if (lane < 24) {
        int rl   = (lane * 11) >> 5;        // lane / 3 for lane < 24
        int comp = lane - rl * 3;           // lane % 3
        xpk[(size_t)(wbase + rl) * 8 + 4 + comp] =
            gumbel[(size_t)wbase * 3 + lane];
    }
}

// ---------------- Kernel 2: sequential scan, 16-deep prefetch ---------------
// (same structure as the validated round-3 version: absmax == 0.0)
__device__ __forceinline__ float tanh_fast(float xv) {
    float e = __expf(2.0f * xv);
    return 1.0f - 2.0f * __builtin_amdgcn_rcpf(e + 1.0f);
}

#define U_PF 16   // prefetch depth; 2 loads/step * 16 = 32 outstanding < 63

__global__ __launch_bounds__(64) void k_scan(
    const float* __restrict__ xpk,     // (S*B, 8) packed: xp | gumbel
    const float* __restrict__ W_hh,    // (3,3)
    const float* __restrict__ signal,  // (3,1)
    float* __restrict__ out)           // [S*B delta] ++ [B*3 hidden]
{
    int b = blockIdx.x * 64 + threadIdx.x;   // 0..511

    float w00 = W_hh[0], w01 = W_hh[1], w02 = W_hh[2];
    float w10 = W_hh[3], w11 = W_hh[4], w12 = W_hh[5];
    float w20 = W_hh[6], w21 = W_hh[7], w22 = W_hh[8];
    float s0v = signal[0], s1v = signal[1], s2v = signal[2];

    float h0 = 0.f, h1 = 0.f, h2 = 0.f;

    const float4* xg = (const float4*)xpk;   // row r: xg[2r] = xp, xg[2r+1] = g

    // Rotating register pipeline (compile-time indices only -> stays in VGPRs).
    float4 bufx[U_PF], bufg[U_PF];
#pragma unroll
    for (int i = 0; i < U_PF; ++i) {
        size_t r = (size_t)i * B_DIM + b;
        bufx[i] = xg[2 * r];
        bufg[i] = xg[2 * r + 1];
    }

#define STEP(sidx, xv, gv)                                                  \
    {                                                                       \
        float a0 = xv.x + w00 * h0 + w01 * h1 + w02 * h2;                   \
        float a1 = xv.y + w10 * h0 + w11 * h1 + w12 * h2;                   \
        float a2 = xv.z + w20 * h0 + w21 * h1 + w22 * h2;                   \
        h0 = tanh_fast(a0);                                                 \
        h1 = tanh_fast(a1);                                                 \
        h2 = tanh_fast(a2);                                                 \
        float l0 = h0 + gv.x, l1 = h1 + gv.y, l2 = h2 + gv.z;               \
        float d = (l2 > l0 && l2 > l1) ? s2v : ((l1 > l0) ? s1v : s0v);     \
        out[(sidx) * B_DIM + b] = d;                                        \
    }

    for (int s0 = 0; s0 < S_DIM - U_PF; s0 += U_PF) {
#pragma unroll
        for (int i = 0; i < U_PF; ++i) {
            float4 xv = bufx[i];
            float4 gv = bufg[i];
            size_t r = (size_t)(s0 + i + U_PF) * B_DIM + b;   // prefetch
            bufx[i] = xg[2 * r];
            bufg[i] = xg[2 * r + 1];
            STEP(s0 + i, xv, gv)
        }
    }
    // Epilogue: last U_PF steps, no prefetch.
#pragma unroll
    for (int i = 0; i < U_PF; ++i) {
        float4 xv = bufx[i];
        float4 gv = bufg[i];
        STEP(S_DIM - U_PF + i, xv, gv)
    }
#undef STEP

    float* hid = out + (size_t)S_DIM * B_DIM + (size_t)b * 3;
    hid[0] = h0; hid[1] = h1; hid[2] = h2;
}

extern "C" void kernel_launch(void* const* d_in, const int* in_sizes, int n_in,
                              void* d_out, int out_size, void* d_ws, size_t ws_size,
                              hipStream_t stream) {
    const float* x      = (const float*)d_in[0];
    const float* gumbel = (const float*)d_in[1];
    const float* W_ih   = (const float*)d_in[2];
    const float* W_hh   = (const float*)d_in[3];
    const float* b_ih   = (const float*)d_in[4];
    const float* b_hh   = (const float*)d_in[5];
    const float* signal = (const float*)d_in[6];

    float* xpk = (float*)d_ws;                    // S*B*8 floats = 16 MB
    float* out = (float*)d_out;

    // 8 lanes per row -> S*B*8 threads.
    k_inproj<<<(S_DIM * B_DIM * 8) / 256, 256, 0, stream>>>(
        x, gumbel, W_ih, b_ih, b_hh, xpk);
    k_scan<<<B_DIM / 64, 64, 0, stream>>>(xpk, W_hh, signal, out);
}